// Round 1
// baseline (1196.121 us; speedup 1.0000x reference)
//
#include <hip/hip_runtime.h>
#include <hip/hip_bf16.h>
#include <math.h>

// Problem constants (fixed by the reference file).
constexpr int N_NODES = 100000;
constexpr int N_EDGES = 3200000;
constexpr int F_IN    = 512;
constexpr int HID     = 16;   // HIDDEN == N_CLASSES == 16

constexpr int NPAD = 100352;  // N_NODES rounded up, workspace slot size (words)

// ---------------------------------------------------------------------------
// K1: degree histogram over dst (deg counts in-edges; +1 self-loop added later)
__global__ __launch_bounds__(256) void deg_kernel(const int* __restrict__ dst,
                                                  int* __restrict__ deg) {
    int e = blockIdx.x * 256 + threadIdx.x;
    if (e < N_EDGES) atomicAdd(&deg[dst[e]], 1);
}

// ---------------------------------------------------------------------------
// K2: dinv[i] = rsqrt(deg[i] + 1)
__global__ __launch_bounds__(256) void dinv_kernel(const int* __restrict__ deg,
                                                   float* __restrict__ dinv) {
    int i = blockIdx.x * 256 + threadIdx.x;
    if (i < N_NODES) dinv[i] = rsqrtf((float)deg[i] + 1.0f);
}

// ---------------------------------------------------------------------------
// K3: single-block exclusive scan of deg -> row_start (and a cursor copy)
__global__ __launch_bounds__(1024) void scan_kernel(const int* __restrict__ deg,
                                                    int* __restrict__ row,
                                                    int* __restrict__ cur) {
    __shared__ int partial[1024];
    const int tid = threadIdx.x;
    const int CH = (N_NODES + 1023) / 1024;  // 98
    int lo = tid * CH;
    int hi = lo + CH; if (hi > N_NODES) hi = N_NODES;
    if (lo > N_NODES) lo = N_NODES;
    int s = 0;
    for (int i = lo; i < hi; ++i) s += deg[i];
    partial[tid] = s;
    __syncthreads();
    // Hillis-Steele inclusive scan over 1024 partials
    for (int off = 1; off < 1024; off <<= 1) {
        int v = (tid >= off) ? partial[tid - off] : 0;
        __syncthreads();
        partial[tid] += v;
        __syncthreads();
    }
    int run = (tid == 0) ? 0 : partial[tid - 1];  // exclusive prefix of my chunk
    for (int i = lo; i < hi; ++i) {
        row[i] = run; cur[i] = run;
        run += deg[i];
    }
    if (tid == 1023) row[N_NODES] = run;  // == N_EDGES
}

// ---------------------------------------------------------------------------
// K4: GEMM1  h = x @ W1 ;  agg1 = h*dinv^2 + b1  (self-loop + bias init)
// Block = 256 (4 waves). Wave handles 4 nodes. Lane = (g,j): g=k-group(0..3),
// j=feature(0..15). W1 staged in LDS with per-group base g*2064 so a wave's
// read banks are {j, j+16} -> 2 lanes/bank (free).
__global__ __launch_bounds__(256) void gemm1_kernel(const float* __restrict__ x,
                                                    const float* __restrict__ W1,
                                                    const float* __restrict__ b1,
                                                    const float* __restrict__ dinv,
                                                    float* __restrict__ h,
                                                    float* __restrict__ agg1) {
    __shared__ float w1s[3 * 2064 + 2048];  // 8240 words = 32.96 KB
    const int tid = threadIdx.x;
    // stage W1: word i = k*16 + jw  ->  (k>>7)*2064 + (k&127)*16 + jw
    for (int i = tid * 4; i < F_IN * HID; i += 256 * 4) {
        float4 v = *(const float4*)(W1 + i);
        int k = i >> 4, jw = i & 15;
        *(float4*)(w1s + (k >> 7) * 2064 + (k & 127) * 16 + jw) = v;
    }
    __syncthreads();

    const int wave = tid >> 6;
    const int lane = tid & 63;
    const int g = lane >> 4;   // k-group: rows g*128 .. g*128+127
    const int j = lane & 15;   // output feature
    const int node0 = blockIdx.x * 16 + wave * 4;

    const float* xr0 = x + (size_t)(node0 + 0) * F_IN + g * 128;
    const float* xr1 = x + (size_t)(node0 + 1) * F_IN + g * 128;
    const float* xr2 = x + (size_t)(node0 + 2) * F_IN + g * 128;
    const float* xr3 = x + (size_t)(node0 + 3) * F_IN + g * 128;
    const float* wg = w1s + g * 2064 + j;

    float acc0 = 0.f, acc1 = 0.f, acc2 = 0.f, acc3 = 0.f;
    #pragma unroll 4
    for (int kk = 0; kk < 128; kk += 4) {
        float4 a0 = *(const float4*)(xr0 + kk);
        float4 a1 = *(const float4*)(xr1 + kk);
        float4 a2 = *(const float4*)(xr2 + kk);
        float4 a3 = *(const float4*)(xr3 + kk);
        const float* wp = wg + kk * 16;
        float w0 = wp[0], w1v = wp[16], w2v = wp[32], w3v = wp[48];
        acc0 += a0.x * w0 + a0.y * w1v + a0.z * w2v + a0.w * w3v;
        acc1 += a1.x * w0 + a1.y * w1v + a1.z * w2v + a1.w * w3v;
        acc2 += a2.x * w0 + a2.y * w1v + a2.z * w2v + a2.w * w3v;
        acc3 += a3.x * w0 + a3.y * w1v + a3.z * w2v + a3.w * w3v;
    }
    // reduce across the 4 k-groups (xor 16 then 32)
    acc0 += __shfl_xor(acc0, 16); acc0 += __shfl_xor(acc0, 32);
    acc1 += __shfl_xor(acc1, 16); acc1 += __shfl_xor(acc1, 32);
    acc2 += __shfl_xor(acc2, 16); acc2 += __shfl_xor(acc2, 32);
    acc3 += __shfl_xor(acc3, 16); acc3 += __shfl_xor(acc3, 32);

    if (g == 0) {
        float b1j = b1[j];
        float dv, sl;
        size_t o;
        dv = dinv[node0 + 0]; sl = dv * dv; o = (size_t)(node0 + 0) * 16 + j;
        h[o] = acc0; agg1[o] = acc0 * sl + b1j;
        dv = dinv[node0 + 1]; sl = dv * dv; o = (size_t)(node0 + 1) * 16 + j;
        h[o] = acc1; agg1[o] = acc1 * sl + b1j;
        dv = dinv[node0 + 2]; sl = dv * dv; o = (size_t)(node0 + 2) * 16 + j;
        h[o] = acc2; agg1[o] = acc2 * sl + b1j;
        dv = dinv[node0 + 3]; sl = dv * dv; o = (size_t)(node0 + 3) * 16 + j;
        h[o] = acc3; agg1[o] = acc3 * sl + b1j;
    }
}

// ---------------------------------------------------------------------------
// K5: CSR build — scatter src into per-dst slots via cursor atomics
__global__ __launch_bounds__(256) void csr_build_kernel(const int* __restrict__ src,
                                                        const int* __restrict__ dst,
                                                        int* __restrict__ cur,
                                                        int* __restrict__ csr) {
    int e = blockIdx.x * 256 + threadIdx.x;
    if (e < N_EDGES) {
        int d = dst[e];
        int pos = atomicAdd(&cur[d], 1);
        csr[pos] = src[e];
    }
}

// ---------------------------------------------------------------------------
// K6/K8: pull aggregation.  agg[i][j] += dinv[i] * sum_{s in nbr(i)} dinv[s]*feat[s][j]
// 16 lanes per node (j = feature), 4 nodes per wave.
__global__ __launch_bounds__(256) void pull_kernel(const float* __restrict__ feat,
                                                   const float* __restrict__ dinv,
                                                   const int* __restrict__ row,
                                                   const int* __restrict__ csr,
                                                   float* __restrict__ agg) {
    int t = blockIdx.x * 256 + threadIdx.x;
    int node = t >> 4;
    int j = t & 15;
    if (node >= N_NODES) return;
    int p = row[node], end = row[node + 1];
    float acc = 0.f;
    for (; p < end; ++p) {
        int s = csr[p];
        acc += feat[(size_t)s * 16 + j] * dinv[s];
    }
    agg[(size_t)node * 16 + j] += dinv[node] * acc;
}

// ---------------------------------------------------------------------------
// K7: layer 2 — h1 = relu(agg1); h2 = h1 @ W2; agg2 = h2*dinv^2 + b2
__global__ __launch_bounds__(256) void layer2_kernel(const float* __restrict__ agg1,
                                                     const float* __restrict__ W2,
                                                     const float* __restrict__ b2,
                                                     const float* __restrict__ dinv,
                                                     float* __restrict__ h2,
                                                     float* __restrict__ agg2) {
    __shared__ float w2s[256];
    __shared__ float b2s[16];
    const int tid = threadIdx.x;
    w2s[tid] = W2[tid];
    if (tid < 16) b2s[tid] = b2[tid];
    __syncthreads();
    int i = blockIdx.x * 256 + tid;
    if (i >= N_NODES) return;
    float v[16];
    const float4* ar = (const float4*)(agg1 + (size_t)i * 16);
    float4 r0 = ar[0], r1 = ar[1], r2 = ar[2], r3 = ar[3];
    v[0]=r0.x; v[1]=r0.y; v[2]=r0.z; v[3]=r0.w;
    v[4]=r1.x; v[5]=r1.y; v[6]=r1.z; v[7]=r1.w;
    v[8]=r2.x; v[9]=r2.y; v[10]=r2.z; v[11]=r2.w;
    v[12]=r3.x; v[13]=r3.y; v[14]=r3.z; v[15]=r3.w;
    #pragma unroll
    for (int k = 0; k < 16; ++k) v[k] = fmaxf(v[k], 0.f);
    float dv = dinv[i], dv2 = dv * dv;
    float o[16];
    #pragma unroll
    for (int jj = 0; jj < 16; ++jj) {
        float s = 0.f;
        #pragma unroll
        for (int k = 0; k < 16; ++k) s += v[k] * w2s[k * 16 + jj];
        o[jj] = s;
    }
    float4* ho = (float4*)(h2 + (size_t)i * 16);
    float4* ao = (float4*)(agg2 + (size_t)i * 16);
    ho[0] = make_float4(o[0], o[1], o[2], o[3]);
    ho[1] = make_float4(o[4], o[5], o[6], o[7]);
    ho[2] = make_float4(o[8], o[9], o[10], o[11]);
    ho[3] = make_float4(o[12], o[13], o[14], o[15]);
    ao[0] = make_float4(o[0]*dv2+b2s[0],  o[1]*dv2+b2s[1],  o[2]*dv2+b2s[2],  o[3]*dv2+b2s[3]);
    ao[1] = make_float4(o[4]*dv2+b2s[4],  o[5]*dv2+b2s[5],  o[6]*dv2+b2s[6],  o[7]*dv2+b2s[7]);
    ao[2] = make_float4(o[8]*dv2+b2s[8],  o[9]*dv2+b2s[9],  o[10]*dv2+b2s[10],o[11]*dv2+b2s[11]);
    ao[3] = make_float4(o[12]*dv2+b2s[12],o[13]*dv2+b2s[13],o[14]*dv2+b2s[14],o[15]*dv2+b2s[15]);
}

// ---------------------------------------------------------------------------
// K9: log_softmax over 16 classes
__global__ __launch_bounds__(256) void lsm_kernel(const float* __restrict__ agg2,
                                                  float* __restrict__ out) {
    int i = blockIdx.x * 256 + threadIdx.x;
    if (i >= N_NODES) return;
    float v[16];
    const float4* ar = (const float4*)(agg2 + (size_t)i * 16);
    float4 r0 = ar[0], r1 = ar[1], r2 = ar[2], r3 = ar[3];
    v[0]=r0.x; v[1]=r0.y; v[2]=r0.z; v[3]=r0.w;
    v[4]=r1.x; v[5]=r1.y; v[6]=r1.z; v[7]=r1.w;
    v[8]=r2.x; v[9]=r2.y; v[10]=r2.z; v[11]=r2.w;
    v[12]=r3.x; v[13]=r3.y; v[14]=r3.z; v[15]=r3.w;
    float m = v[0];
    #pragma unroll
    for (int k = 1; k < 16; ++k) m = fmaxf(m, v[k]);
    float ssum = 0.f;
    #pragma unroll
    for (int k = 0; k < 16; ++k) ssum += expf(v[k] - m);
    float l = m + logf(ssum);
    float4* oo = (float4*)(out + (size_t)i * 16);
    oo[0] = make_float4(v[0]-l, v[1]-l, v[2]-l, v[3]-l);
    oo[1] = make_float4(v[4]-l, v[5]-l, v[6]-l, v[7]-l);
    oo[2] = make_float4(v[8]-l, v[9]-l, v[10]-l, v[11]-l);
    oo[3] = make_float4(v[12]-l, v[13]-l, v[14]-l, v[15]-l);
}

// ---------------------------------------------------------------------------
extern "C" void kernel_launch(void* const* d_in, const int* in_sizes, int n_in,
                              void* d_out, int out_size, void* d_ws, size_t ws_size,
                              hipStream_t stream) {
    const float* x    = (const float*)d_in[0];
    const float* W1   = (const float*)d_in[1];
    const float* b1   = (const float*)d_in[2];
    const float* W2   = (const float*)d_in[3];
    const float* b2   = (const float*)d_in[4];
    const int*   ei   = (const int*)d_in[5];
    const int*   src  = ei;             // edge_index[0]
    const int*   dst  = ei + N_EDGES;   // edge_index[1]
    float* out = (float*)d_out;

    // workspace layout (4-byte words); total ~40 MB
    int*   wsi  = (int*)d_ws;
    float* wsf  = (float*)d_ws;
    int*   deg  = wsi;                         // [NPAD]
    int*   row  = wsi + NPAD;                  // [NPAD] (uses N+1)
    int*   cur  = wsi + 2 * NPAD;              // [NPAD]
    float* dinv = wsf + 3 * NPAD;              // [NPAD]
    int*   csr  = wsi + 4 * NPAD;              // [E]
    float* h    = wsf + 4 * NPAD + N_EDGES;            // [N*16]
    float* agg1 = h    + (size_t)N_NODES * 16;         // [N*16]
    float* h2   = agg1 + (size_t)N_NODES * 16;         // [N*16]
    float* agg2 = h2   + (size_t)N_NODES * 16;         // [N*16]

    const int EB = (N_EDGES + 255) / 256;      // 12500
    const int NB = (N_NODES + 255) / 256;      // 391
    const int GB = N_NODES / 16;               // 6250 (exact)

    hipMemsetAsync(deg, 0, NPAD * sizeof(int), stream);
    deg_kernel<<<EB, 256, 0, stream>>>(dst, deg);
    dinv_kernel<<<NB, 256, 0, stream>>>(deg, dinv);
    scan_kernel<<<1, 1024, 0, stream>>>(deg, row, cur);
    gemm1_kernel<<<GB, 256, 0, stream>>>(x, W1, b1, dinv, h, agg1);
    csr_build_kernel<<<EB, 256, 0, stream>>>(src, dst, cur, csr);
    pull_kernel<<<GB, 256, 0, stream>>>(h, dinv, row, csr, agg1);
    layer2_kernel<<<NB, 256, 0, stream>>>(agg1, W2, b2, dinv, h2, agg2);
    pull_kernel<<<GB, 256, 0, stream>>>(h2, dinv, row, csr, agg2);
    lsm_kernel<<<NB, 256, 0, stream>>>(agg2, out);
}

// Round 2
// 561.105 us; speedup vs baseline: 2.1317x; 2.1317x over previous
//
#include <hip/hip_runtime.h>
#include <hip/hip_bf16.h>
#include <math.h>

// Problem constants (fixed by the reference file).
constexpr int N_NODES = 100000;
constexpr int N_EDGES = 3200000;
constexpr int F_IN    = 512;
constexpr int HID     = 16;   // HIDDEN == N_CLASSES == 16

constexpr int NPAD = 100352;  // N_NODES rounded up (words)

// Binning parameters: bucket = dst >> 8 (256 nodes/bucket)
constexpr int B_BITS = 8;
constexpr int NPB    = 1 << B_BITS;                    // 256 nodes per bucket
constexpr int NBKT   = (N_NODES + NPB - 1) / NPB;      // 391 buckets
constexpr int SBLK   = 400;                            // scatter blocks
constexpr int CHUNK  = N_EDGES / SBLK;                 // 8000 edges/block (exact)
constexpr int MAX_BKT_E = 12288;  // mean 8184, sd ~90 -> +45 sd safety; 48KB LDS

// ---------------------------------------------------------------------------
// K1: per-block LDS histogram of dst-buckets -> global bucket counts.
// 156K global atomics instead of 3.2M.
__global__ __launch_bounds__(1024) void bin_count_kernel(const int* __restrict__ dst,
                                                         int* __restrict__ gcnt) {
    __shared__ int cnt[NBKT];
    const int tid = threadIdx.x;
    for (int t = tid; t < NBKT; t += 1024) cnt[t] = 0;
    __syncthreads();
    const int base = blockIdx.x * CHUNK;
    for (int i = tid; i < CHUNK; i += 1024)
        atomicAdd(&cnt[dst[base + i] >> B_BITS], 1);
    __syncthreads();
    for (int t = tid; t < NBKT; t += 1024)
        if (cnt[t]) atomicAdd(&gcnt[t], cnt[t]);
}

// ---------------------------------------------------------------------------
// K2: scan 391 bucket counts -> bucket base offsets (+ cursor copy). 1 block.
__global__ __launch_bounds__(512) void bucket_scan_kernel(const int* __restrict__ gcnt,
                                                          int* __restrict__ bbase,
                                                          int* __restrict__ gcur) {
    __shared__ int s[512];
    const int tid = threadIdx.x;
    s[tid] = (tid < NBKT) ? gcnt[tid] : 0;
    __syncthreads();
    for (int off = 1; off < 512; off <<= 1) {
        int v = (tid >= off) ? s[tid - off] : 0;
        __syncthreads();
        s[tid] += v;
        __syncthreads();
    }
    int excl = (tid == 0) ? 0 : s[tid - 1];
    if (tid <= NBKT) bbase[tid] = excl;
    if (tid <  NBKT) gcur[tid]  = excl;
}

// ---------------------------------------------------------------------------
// K3: scatter edges into bucket-grouped array. Per-block histogram -> one
// global reservation per (block,bucket) -> LDS-cursor scatter. Writes land in
// 391 append regions (each hot in L2), packed as (local_dst<<24 | src).
__global__ __launch_bounds__(1024) void bin_scatter_kernel(const int* __restrict__ src,
                                                           const int* __restrict__ dst,
                                                           int* __restrict__ gcur,
                                                           unsigned int* __restrict__ binned) {
    __shared__ int cnt[NBKT];
    __shared__ int cur[NBKT];
    const int tid = threadIdx.x;
    for (int t = tid; t < NBKT; t += 1024) cnt[t] = 0;
    __syncthreads();
    const int base = blockIdx.x * CHUNK;
    for (int i = tid; i < CHUNK; i += 1024)
        atomicAdd(&cnt[dst[base + i] >> B_BITS], 1);
    __syncthreads();
    for (int t = tid; t < NBKT; t += 1024)
        cur[t] = cnt[t] ? atomicAdd(&gcur[t], cnt[t]) : 0;
    __syncthreads();
    for (int i = tid; i < CHUNK; i += 1024) {
        int d = dst[base + i];
        int b = d >> B_BITS;
        int pos = atomicAdd(&cur[b], 1);
        binned[pos] = ((unsigned)(d & (NPB - 1)) << 24) | (unsigned)src[base + i];
    }
}

// ---------------------------------------------------------------------------
// K4: one block per bucket. Stage bucket edges in LDS, local histogram + scan
// entirely in LDS, then write: dinv, row, and csr (in-place over binned —
// safe because edges were copied to LDS first). All global writes sequential
// or localized to the bucket's ~32KB csr region.
__global__ __launch_bounds__(1024) void csr_bucket_kernel(const unsigned int* __restrict__ binned,
                                                          const int* __restrict__ bbase,
                                                          int* __restrict__ row,
                                                          int* __restrict__ csr,
                                                          float* __restrict__ dinv) {
    __shared__ unsigned int eb[MAX_BKT_E];
    __shared__ int deg[NPB];
    __shared__ int pre[NPB];
    __shared__ int cur[NPB];
    const int tid = threadIdx.x;
    const int b = blockIdx.x;
    const int e0 = bbase[b];
    int ne = bbase[b + 1] - e0;
    if (ne > MAX_BKT_E) ne = MAX_BKT_E;  // safety (statistically impossible)

    if (tid < NPB) deg[tid] = 0;
    for (int i = tid; i < ne; i += 1024) eb[i] = binned[e0 + i];
    __syncthreads();
    for (int i = tid; i < ne; i += 1024)
        atomicAdd(&deg[eb[i] >> 24], 1);
    __syncthreads();
    // exclusive scan over 256 local degrees (Hillis-Steele, inclusive then shift)
    if (tid < NPB) pre[tid] = deg[tid];
    __syncthreads();
    for (int off = 1; off < NPB; off <<= 1) {
        int v = 0;
        if (tid < NPB && tid >= off) v = pre[tid - off];
        __syncthreads();
        if (tid < NPB) pre[tid] += v;
        __syncthreads();
    }
    if (tid < NPB) {
        int excl = (tid == 0) ? 0 : pre[tid - 1];
        int g = e0 + excl;
        cur[tid] = g;
        int node = b * NPB + tid;
        if (node < N_NODES) {
            row[node] = g;
            dinv[node] = rsqrtf((float)deg[tid] + 1.0f);
        }
    }
    if (b == 0 && tid == 0) row[N_NODES] = N_EDGES;
    __syncthreads();
    for (int i = tid; i < ne; i += 1024) {
        unsigned int v = eb[i];
        int pos = atomicAdd(&cur[v >> 24], 1);
        csr[pos] = (int)(v & 0xFFFFFFu);
    }
}

// ---------------------------------------------------------------------------
// K5: GEMM1  h = x @ W1 ; writes hh = h*dinv (premultiplied for pull) and
// agg1 = h*dinv^2 + b1 (self-loop + bias init).
__global__ __launch_bounds__(256) void gemm1_kernel(const float* __restrict__ x,
                                                    const float* __restrict__ W1,
                                                    const float* __restrict__ b1,
                                                    const float* __restrict__ dinv,
                                                    float* __restrict__ hh,
                                                    float* __restrict__ agg1) {
    __shared__ float w1s[3 * 2064 + 2048];  // per-group base g*2064 -> banks {j, j+16}
    const int tid = threadIdx.x;
    for (int i = tid * 4; i < F_IN * HID; i += 256 * 4) {
        float4 v = *(const float4*)(W1 + i);
        int k = i >> 4, jw = i & 15;
        *(float4*)(w1s + (k >> 7) * 2064 + (k & 127) * 16 + jw) = v;
    }
    __syncthreads();

    const int wave = tid >> 6;
    const int lane = tid & 63;
    const int g = lane >> 4;   // k-group: rows g*128 .. g*128+127
    const int j = lane & 15;   // output feature
    const int node0 = blockIdx.x * 16 + wave * 4;

    const float* xr0 = x + (size_t)(node0 + 0) * F_IN + g * 128;
    const float* xr1 = x + (size_t)(node0 + 1) * F_IN + g * 128;
    const float* xr2 = x + (size_t)(node0 + 2) * F_IN + g * 128;
    const float* xr3 = x + (size_t)(node0 + 3) * F_IN + g * 128;
    const float* wg = w1s + g * 2064 + j;

    float acc0 = 0.f, acc1 = 0.f, acc2 = 0.f, acc3 = 0.f;
    #pragma unroll 4
    for (int kk = 0; kk < 128; kk += 4) {
        float4 a0 = *(const float4*)(xr0 + kk);
        float4 a1 = *(const float4*)(xr1 + kk);
        float4 a2 = *(const float4*)(xr2 + kk);
        float4 a3 = *(const float4*)(xr3 + kk);
        const float* wp = wg + kk * 16;
        float w0 = wp[0], w1v = wp[16], w2v = wp[32], w3v = wp[48];
        acc0 += a0.x * w0 + a0.y * w1v + a0.z * w2v + a0.w * w3v;
        acc1 += a1.x * w0 + a1.y * w1v + a1.z * w2v + a1.w * w3v;
        acc2 += a2.x * w0 + a2.y * w1v + a2.z * w2v + a2.w * w3v;
        acc3 += a3.x * w0 + a3.y * w1v + a3.z * w2v + a3.w * w3v;
    }
    acc0 += __shfl_xor(acc0, 16); acc0 += __shfl_xor(acc0, 32);
    acc1 += __shfl_xor(acc1, 16); acc1 += __shfl_xor(acc1, 32);
    acc2 += __shfl_xor(acc2, 16); acc2 += __shfl_xor(acc2, 32);
    acc3 += __shfl_xor(acc3, 16); acc3 += __shfl_xor(acc3, 32);

    if (g == 0) {
        float b1j = b1[j];
        float dv, hv;
        size_t o;
        dv = dinv[node0 + 0]; hv = acc0 * dv; o = (size_t)(node0 + 0) * 16 + j;
        hh[o] = hv; agg1[o] = hv * dv + b1j;
        dv = dinv[node0 + 1]; hv = acc1 * dv; o = (size_t)(node0 + 1) * 16 + j;
        hh[o] = hv; agg1[o] = hv * dv + b1j;
        dv = dinv[node0 + 2]; hv = acc2 * dv; o = (size_t)(node0 + 2) * 16 + j;
        hh[o] = hv; agg1[o] = hv * dv + b1j;
        dv = dinv[node0 + 3]; hv = acc3 * dv; o = (size_t)(node0 + 3) * 16 + j;
        hh[o] = hv; agg1[o] = hv * dv + b1j;
    }
}

// ---------------------------------------------------------------------------
// K6/K8: pull aggregation. agg[i][j] += dinv[i] * sum_{s in nbr(i)} hh[s][j]
// (hh already premultiplied by dinv[src]). 16 lanes per node, 4x unroll for MLP.
__global__ __launch_bounds__(256) void pull_kernel(const float* __restrict__ hh,
                                                   const float* __restrict__ dinv,
                                                   const int* __restrict__ row,
                                                   const int* __restrict__ csr,
                                                   float* __restrict__ agg) {
    int t = blockIdx.x * 256 + threadIdx.x;
    int node = t >> 4;
    int j = t & 15;
    if (node >= N_NODES) return;
    int p = row[node], end = row[node + 1];
    float a0 = 0.f, a1 = 0.f, a2 = 0.f, a3 = 0.f;
    for (; p + 4 <= end; p += 4) {
        int s0 = csr[p], s1 = csr[p + 1], s2 = csr[p + 2], s3 = csr[p + 3];
        a0 += hh[(s0 << 4) + j];
        a1 += hh[(s1 << 4) + j];
        a2 += hh[(s2 << 4) + j];
        a3 += hh[(s3 << 4) + j];
    }
    for (; p < end; ++p) a0 += hh[(csr[p] << 4) + j];
    float acc = (a0 + a1) + (a2 + a3);
    agg[(node << 4) + j] += dinv[node] * acc;
}

// ---------------------------------------------------------------------------
// K7: layer 2 — h1 = relu(agg1); h2 = h1 @ W2; hh2 = h2*dinv; agg2 = h2*dinv^2 + b2
__global__ __launch_bounds__(256) void layer2_kernel(const float* __restrict__ agg1,
                                                     const float* __restrict__ W2,
                                                     const float* __restrict__ b2,
                                                     const float* __restrict__ dinv,
                                                     float* __restrict__ hh2,
                                                     float* __restrict__ agg2) {
    __shared__ float w2s[256];
    __shared__ float b2s[16];
    const int tid = threadIdx.x;
    w2s[tid] = W2[tid];
    if (tid < 16) b2s[tid] = b2[tid];
    __syncthreads();
    int i = blockIdx.x * 256 + tid;
    if (i >= N_NODES) return;
    float v[16];
    const float4* ar = (const float4*)(agg1 + (size_t)i * 16);
    float4 r0 = ar[0], r1 = ar[1], r2 = ar[2], r3 = ar[3];
    v[0]=r0.x; v[1]=r0.y; v[2]=r0.z; v[3]=r0.w;
    v[4]=r1.x; v[5]=r1.y; v[6]=r1.z; v[7]=r1.w;
    v[8]=r2.x; v[9]=r2.y; v[10]=r2.z; v[11]=r2.w;
    v[12]=r3.x; v[13]=r3.y; v[14]=r3.z; v[15]=r3.w;
    #pragma unroll
    for (int k = 0; k < 16; ++k) v[k] = fmaxf(v[k], 0.f);
    float dv = dinv[i], dv2 = dv * dv;
    float o[16];
    #pragma unroll
    for (int jj = 0; jj < 16; ++jj) {
        float s = 0.f;
        #pragma unroll
        for (int k = 0; k < 16; ++k) s += v[k] * w2s[k * 16 + jj];
        o[jj] = s;
    }
    float4* ho = (float4*)(hh2 + (size_t)i * 16);
    float4* ao = (float4*)(agg2 + (size_t)i * 16);
    ho[0] = make_float4(o[0]*dv,  o[1]*dv,  o[2]*dv,  o[3]*dv);
    ho[1] = make_float4(o[4]*dv,  o[5]*dv,  o[6]*dv,  o[7]*dv);
    ho[2] = make_float4(o[8]*dv,  o[9]*dv,  o[10]*dv, o[11]*dv);
    ho[3] = make_float4(o[12]*dv, o[13]*dv, o[14]*dv, o[15]*dv);
    ao[0] = make_float4(o[0]*dv2+b2s[0],  o[1]*dv2+b2s[1],  o[2]*dv2+b2s[2],  o[3]*dv2+b2s[3]);
    ao[1] = make_float4(o[4]*dv2+b2s[4],  o[5]*dv2+b2s[5],  o[6]*dv2+b2s[6],  o[7]*dv2+b2s[7]);
    ao[2] = make_float4(o[8]*dv2+b2s[8],  o[9]*dv2+b2s[9],  o[10]*dv2+b2s[10],o[11]*dv2+b2s[11]);
    ao[3] = make_float4(o[12]*dv2+b2s[12],o[13]*dv2+b2s[13],o[14]*dv2+b2s[14],o[15]*dv2+b2s[15]);
}

// ---------------------------------------------------------------------------
// K9: log_softmax over 16 classes
__global__ __launch_bounds__(256) void lsm_kernel(const float* __restrict__ agg2,
                                                  float* __restrict__ out) {
    int i = blockIdx.x * 256 + threadIdx.x;
    if (i >= N_NODES) return;
    float v[16];
    const float4* ar = (const float4*)(agg2 + (size_t)i * 16);
    float4 r0 = ar[0], r1 = ar[1], r2 = ar[2], r3 = ar[3];
    v[0]=r0.x; v[1]=r0.y; v[2]=r0.z; v[3]=r0.w;
    v[4]=r1.x; v[5]=r1.y; v[6]=r1.z; v[7]=r1.w;
    v[8]=r2.x; v[9]=r2.y; v[10]=r2.z; v[11]=r2.w;
    v[12]=r3.x; v[13]=r3.y; v[14]=r3.z; v[15]=r3.w;
    float m = v[0];
    #pragma unroll
    for (int k = 1; k < 16; ++k) m = fmaxf(m, v[k]);
    float ssum = 0.f;
    #pragma unroll
    for (int k = 0; k < 16; ++k) ssum += expf(v[k] - m);
    float l = m + logf(ssum);
    float4* oo = (float4*)(out + (size_t)i * 16);
    oo[0] = make_float4(v[0]-l, v[1]-l, v[2]-l, v[3]-l);
    oo[1] = make_float4(v[4]-l, v[5]-l, v[6]-l, v[7]-l);
    oo[2] = make_float4(v[8]-l, v[9]-l, v[10]-l, v[11]-l);
    oo[3] = make_float4(v[12]-l, v[13]-l, v[14]-l, v[15]-l);
}

// ---------------------------------------------------------------------------
extern "C" void kernel_launch(void* const* d_in, const int* in_sizes, int n_in,
                              void* d_out, int out_size, void* d_ws, size_t ws_size,
                              hipStream_t stream) {
    const float* x    = (const float*)d_in[0];
    const float* W1   = (const float*)d_in[1];
    const float* b1   = (const float*)d_in[2];
    const float* W2   = (const float*)d_in[3];
    const float* b2   = (const float*)d_in[4];
    const int*   ei   = (const int*)d_in[5];
    const int*   src  = ei;             // edge_index[0]
    const int*   dst  = ei + N_EDGES;   // edge_index[1]
    float* out = (float*)d_out;

    // workspace layout (4-byte words); total ~39.2 MB
    int*   wsi  = (int*)d_ws;
    float* wsf  = (float*)d_ws;
    int*   gcnt  = wsi;                        // [NBKT]
    int*   bbase = wsi + 512;                  // [NBKT+1]
    int*   gcur  = wsi + 1024;                 // [NBKT]
    float* dinv  = wsf + 2048;                 // [NPAD]
    int*   row   = wsi + 2048 + NPAD;          // [N+1]
    int*   csr   = wsi + 2048 + 2 * NPAD;      // [E]  (binned & csr share this)
    unsigned int* binned = (unsigned int*)csr;
    float* hh    = wsf + 2048 + 2 * NPAD + N_EDGES;    // [N*16]
    float* agg1  = hh   + (size_t)N_NODES * 16;        // [N*16]
    float* hh2   = agg1 + (size_t)N_NODES * 16;        // [N*16]
    float* agg2  = hh2  + (size_t)N_NODES * 16;        // [N*16]

    const int NB = (N_NODES + 255) / 256;      // 391
    const int GB = N_NODES / 16;               // 6250 (exact)

    hipMemsetAsync(gcnt, 0, NBKT * sizeof(int), stream);
    bin_count_kernel <<<SBLK, 1024, 0, stream>>>(dst, gcnt);
    bucket_scan_kernel<<<1, 512, 0, stream>>>(gcnt, bbase, gcur);
    bin_scatter_kernel<<<SBLK, 1024, 0, stream>>>(src, dst, gcur, binned);
    csr_bucket_kernel<<<NBKT, 1024, 0, stream>>>(binned, bbase, row, csr, dinv);
    gemm1_kernel<<<GB, 256, 0, stream>>>(x, W1, b1, dinv, hh, agg1);
    pull_kernel<<<GB, 256, 0, stream>>>(hh, dinv, row, csr, agg1);
    layer2_kernel<<<NB, 256, 0, stream>>>(agg1, W2, b2, dinv, hh2, agg2);
    pull_kernel<<<GB, 256, 0, stream>>>(hh2, dinv, row, csr, agg2);
    lsm_kernel<<<NB, 256, 0, stream>>>(agg2, out);
}

// Round 3
// 495.815 us; speedup vs baseline: 2.4124x; 1.1317x over previous
//
#include <hip/hip_runtime.h>
#include <hip/hip_bf16.h>
#include <math.h>

// Problem constants (fixed by the reference file).
constexpr int N_NODES = 100000;
constexpr int N_EDGES = 3200000;
constexpr int F_IN    = 512;
constexpr int HID     = 16;   // HIDDEN == N_CLASSES == 16

constexpr int NPAD = 100352;  // N_NODES rounded up (words)

// Binning parameters: bucket = dst >> 8 (256 nodes/bucket)
constexpr int B_BITS = 8;
constexpr int NPB    = 1 << B_BITS;                    // 256 nodes per bucket
constexpr int NBKT   = (N_NODES + NPB - 1) / NPB;      // 391 buckets
constexpr int SBLK   = 400;                            // scatter blocks
constexpr int CHUNK  = N_EDGES / SBLK;                 // 8000 edges/block (exact)
constexpr int MAX_BKT_E = 12288;  // mean 8184, sd ~90 -> +45 sd safety; 48KB LDS

// ---------------------------------------------------------------------------
// K1: per-block LDS histogram of dst-buckets -> global bucket counts.
__global__ __launch_bounds__(1024) void bin_count_kernel(const int* __restrict__ dst,
                                                         int* __restrict__ gcnt) {
    __shared__ int cnt[NBKT];
    const int tid = threadIdx.x;
    for (int t = tid; t < NBKT; t += 1024) cnt[t] = 0;
    __syncthreads();
    const int base = blockIdx.x * CHUNK;
    for (int i = tid; i < CHUNK; i += 1024)
        atomicAdd(&cnt[dst[base + i] >> B_BITS], 1);
    __syncthreads();
    for (int t = tid; t < NBKT; t += 1024)
        if (cnt[t]) atomicAdd(&gcnt[t], cnt[t]);
}

// ---------------------------------------------------------------------------
// K2: scan 391 bucket counts -> bucket base offsets (+ cursor copy). 1 block.
__global__ __launch_bounds__(512) void bucket_scan_kernel(const int* __restrict__ gcnt,
                                                          int* __restrict__ bbase,
                                                          int* __restrict__ gcur) {
    __shared__ int s[512];
    const int tid = threadIdx.x;
    s[tid] = (tid < NBKT) ? gcnt[tid] : 0;
    __syncthreads();
    for (int off = 1; off < 512; off <<= 1) {
        int v = (tid >= off) ? s[tid - off] : 0;
        __syncthreads();
        s[tid] += v;
        __syncthreads();
    }
    int excl = (tid == 0) ? 0 : s[tid - 1];
    if (tid <= NBKT) bbase[tid] = excl;
    if (tid <  NBKT) gcur[tid]  = excl;
}

// ---------------------------------------------------------------------------
// K3: scatter edges into bucket-grouped array (writes L2-localized).
__global__ __launch_bounds__(1024) void bin_scatter_kernel(const int* __restrict__ src,
                                                           const int* __restrict__ dst,
                                                           int* __restrict__ gcur,
                                                           unsigned int* __restrict__ binned) {
    __shared__ int cnt[NBKT];
    __shared__ int cur[NBKT];
    const int tid = threadIdx.x;
    for (int t = tid; t < NBKT; t += 1024) cnt[t] = 0;
    __syncthreads();
    const int base = blockIdx.x * CHUNK;
    for (int i = tid; i < CHUNK; i += 1024)
        atomicAdd(&cnt[dst[base + i] >> B_BITS], 1);
    __syncthreads();
    for (int t = tid; t < NBKT; t += 1024)
        cur[t] = cnt[t] ? atomicAdd(&gcur[t], cnt[t]) : 0;
    __syncthreads();
    for (int i = tid; i < CHUNK; i += 1024) {
        int d = dst[base + i];
        int b = d >> B_BITS;
        int pos = atomicAdd(&cur[b], 1);
        binned[pos] = ((unsigned)(d & (NPB - 1)) << 24) | (unsigned)src[base + i];
    }
}

// ---------------------------------------------------------------------------
// K4: one block per bucket: LDS-local CSR build + deg/dinv/row emission.
__global__ __launch_bounds__(1024) void csr_bucket_kernel(const unsigned int* __restrict__ binned,
                                                          const int* __restrict__ bbase,
                                                          int* __restrict__ row,
                                                          int* __restrict__ csr,
                                                          float* __restrict__ dinv) {
    __shared__ unsigned int eb[MAX_BKT_E];
    __shared__ int deg[NPB];
    __shared__ int pre[NPB];
    __shared__ int cur[NPB];
    const int tid = threadIdx.x;
    const int b = blockIdx.x;
    const int e0 = bbase[b];
    int ne = bbase[b + 1] - e0;
    if (ne > MAX_BKT_E) ne = MAX_BKT_E;  // safety (statistically impossible)

    if (tid < NPB) deg[tid] = 0;
    for (int i = tid; i < ne; i += 1024) eb[i] = binned[e0 + i];
    __syncthreads();
    for (int i = tid; i < ne; i += 1024)
        atomicAdd(&deg[eb[i] >> 24], 1);
    __syncthreads();
    if (tid < NPB) pre[tid] = deg[tid];
    __syncthreads();
    for (int off = 1; off < NPB; off <<= 1) {
        int v = 0;
        if (tid < NPB && tid >= off) v = pre[tid - off];
        __syncthreads();
        if (tid < NPB) pre[tid] += v;
        __syncthreads();
    }
    if (tid < NPB) {
        int excl = (tid == 0) ? 0 : pre[tid - 1];
        int g = e0 + excl;
        cur[tid] = g;
        int node = b * NPB + tid;
        if (node < N_NODES) {
            row[node] = g;
            dinv[node] = rsqrtf((float)deg[tid] + 1.0f);
        }
    }
    if (b == 0 && tid == 0) row[N_NODES] = N_EDGES;
    __syncthreads();
    for (int i = tid; i < ne; i += 1024) {
        unsigned int v = eb[i];
        int pos = atomicAdd(&cur[v >> 24], 1);
        csr[pos] = (int)(v & 0xFFFFFFu);
    }
}

// ---------------------------------------------------------------------------
// K5: GEMM1  h = x @ W1 ; writes hh = h*dinv and agg1 = h*dinv^2 + b1.
// NEW: x-tile (16 nodes x 512 f32 = 32 KB, contiguous in global) staged into
// LDS via global_load_lds width=16 (coalesced, 1 KB/wave-instr) instead of
// 16x-redundant per-lane global loads (the R2 L1-bandwidth bottleneck).
// Compute reads x from LDS: 16-lane same-address broadcast is free; the 4
// k-groups rotate their k start by g*8 floats so the 4 distinct b128
// addresses land on disjoint banks (4t+8g mod 32) -> conflict-free.
__global__ __launch_bounds__(256) void gemm1_kernel(const float* __restrict__ x,
                                                    const float* __restrict__ W1,
                                                    const float* __restrict__ b1,
                                                    const float* __restrict__ dinv,
                                                    float* __restrict__ hh,
                                                    float* __restrict__ agg1) {
    __shared__ float xs[16 * 512];          // 32 KB x-tile
    __shared__ float w1s[3 * 2064 + 2048];  // 32.96 KB, group base g*2064 -> banks {j, j+16}
    const int tid = threadIdx.x;

    // stage x-tile: contiguous 32 KB, each thread 16 B per round, 8 rounds
    const float* gsrc = x + (size_t)blockIdx.x * 16 * F_IN;
    #pragma unroll
    for (int r = 0; r < 8; ++r) {
        int off = (r * 256 + tid) * 4;  // float index; = wave-uniform base + lane*4 floats
        __builtin_amdgcn_global_load_lds(
            (const __attribute__((address_space(1))) void*)(gsrc + off),
            (__attribute__((address_space(3))) void*)(xs + off), 16, 0, 0);
    }
    // stage W1 (padded layout): word i = k*16+jw -> (k>>7)*2064 + (k&127)*16 + jw
    for (int i = tid * 4; i < F_IN * HID; i += 256 * 4) {
        float4 v = *(const float4*)(W1 + i);
        int k = i >> 4, jw = i & 15;
        *(float4*)(w1s + (k >> 7) * 2064 + (k & 127) * 16 + jw) = v;
    }
    __syncthreads();  // drains vmcnt (global_load_lds) + lgkmcnt

    const int wave = tid >> 6;
    const int lane = tid & 63;
    const int g = lane >> 4;   // k-group: covers k in [g*128, g*128+128)
    const int j = lane & 15;   // output feature
    const int node0 = blockIdx.x * 16 + wave * 4;

    const float* xr0 = xs + (wave * 4 + 0) * F_IN + g * 128;
    const float* xr1 = xs + (wave * 4 + 1) * F_IN + g * 128;
    const float* xr2 = xs + (wave * 4 + 2) * F_IN + g * 128;
    const float* xr3 = xs + (wave * 4 + 3) * F_IN + g * 128;
    const float* wg = w1s + g * 2064 + j;

    float acc0 = 0.f, acc1 = 0.f, acc2 = 0.f, acc3 = 0.f;
    const int rot = g << 1;  // k-rotation in float4 steps (g*8 floats)
    #pragma unroll 4
    for (int t = 0; t < 32; ++t) {
        const int kk = ((t + rot) & 31) << 2;  // rotated k offset (floats)
        float4 a0 = *(const float4*)(xr0 + kk);
        float4 a1 = *(const float4*)(xr1 + kk);
        float4 a2 = *(const float4*)(xr2 + kk);
        float4 a3 = *(const float4*)(xr3 + kk);
        const float* wp = wg + kk * 16;
        float w0 = wp[0], w1v = wp[16], w2v = wp[32], w3v = wp[48];
        acc0 += a0.x * w0 + a0.y * w1v + a0.z * w2v + a0.w * w3v;
        acc1 += a1.x * w0 + a1.y * w1v + a1.z * w2v + a1.w * w3v;
        acc2 += a2.x * w0 + a2.y * w1v + a2.z * w2v + a2.w * w3v;
        acc3 += a3.x * w0 + a3.y * w1v + a3.z * w2v + a3.w * w3v;
    }
    acc0 += __shfl_xor(acc0, 16); acc0 += __shfl_xor(acc0, 32);
    acc1 += __shfl_xor(acc1, 16); acc1 += __shfl_xor(acc1, 32);
    acc2 += __shfl_xor(acc2, 16); acc2 += __shfl_xor(acc2, 32);
    acc3 += __shfl_xor(acc3, 16); acc3 += __shfl_xor(acc3, 32);

    if (g == 0) {
        float b1j = b1[j];
        float dv, hv;
        size_t o;
        dv = dinv[node0 + 0]; hv = acc0 * dv; o = (size_t)(node0 + 0) * 16 + j;
        hh[o] = hv; agg1[o] = hv * dv + b1j;
        dv = dinv[node0 + 1]; hv = acc1 * dv; o = (size_t)(node0 + 1) * 16 + j;
        hh[o] = hv; agg1[o] = hv * dv + b1j;
        dv = dinv[node0 + 2]; hv = acc2 * dv; o = (size_t)(node0 + 2) * 16 + j;
        hh[o] = hv; agg1[o] = hv * dv + b1j;
        dv = dinv[node0 + 3]; hv = acc3 * dv; o = (size_t)(node0 + 3) * 16 + j;
        hh[o] = hv; agg1[o] = hv * dv + b1j;
    }
}

// ---------------------------------------------------------------------------
// K6/K8: pull aggregation. agg[i][j] += dinv[i] * sum_{s in nbr(i)} hh[s][j]
__global__ __launch_bounds__(256) void pull_kernel(const float* __restrict__ hh,
                                                   const float* __restrict__ dinv,
                                                   const int* __restrict__ row,
                                                   const int* __restrict__ csr,
                                                   float* __restrict__ agg) {
    int t = blockIdx.x * 256 + threadIdx.x;
    int node = t >> 4;
    int j = t & 15;
    if (node >= N_NODES) return;
    int p = row[node], end = row[node + 1];
    float a0 = 0.f, a1 = 0.f, a2 = 0.f, a3 = 0.f;
    for (; p + 4 <= end; p += 4) {
        int s0 = csr[p], s1 = csr[p + 1], s2 = csr[p + 2], s3 = csr[p + 3];
        a0 += hh[(s0 << 4) + j];
        a1 += hh[(s1 << 4) + j];
        a2 += hh[(s2 << 4) + j];
        a3 += hh[(s3 << 4) + j];
    }
    for (; p < end; ++p) a0 += hh[(csr[p] << 4) + j];
    float acc = (a0 + a1) + (a2 + a3);
    agg[(node << 4) + j] += dinv[node] * acc;
}

// ---------------------------------------------------------------------------
// K7: layer 2 — h1 = relu(agg1); h2 = h1 @ W2; hh2 = h2*dinv; agg2 = h2*dinv^2 + b2
__global__ __launch_bounds__(256) void layer2_kernel(const float* __restrict__ agg1,
                                                     const float* __restrict__ W2,
                                                     const float* __restrict__ b2,
                                                     const float* __restrict__ dinv,
                                                     float* __restrict__ hh2,
                                                     float* __restrict__ agg2) {
    __shared__ float w2s[256];
    __shared__ float b2s[16];
    const int tid = threadIdx.x;
    w2s[tid] = W2[tid];
    if (tid < 16) b2s[tid] = b2[tid];
    __syncthreads();
    int i = blockIdx.x * 256 + tid;
    if (i >= N_NODES) return;
    float v[16];
    const float4* ar = (const float4*)(agg1 + (size_t)i * 16);
    float4 r0 = ar[0], r1 = ar[1], r2 = ar[2], r3 = ar[3];
    v[0]=r0.x; v[1]=r0.y; v[2]=r0.z; v[3]=r0.w;
    v[4]=r1.x; v[5]=r1.y; v[6]=r1.z; v[7]=r1.w;
    v[8]=r2.x; v[9]=r2.y; v[10]=r2.z; v[11]=r2.w;
    v[12]=r3.x; v[13]=r3.y; v[14]=r3.z; v[15]=r3.w;
    #pragma unroll
    for (int k = 0; k < 16; ++k) v[k] = fmaxf(v[k], 0.f);
    float dv = dinv[i], dv2 = dv * dv;
    float o[16];
    #pragma unroll
    for (int jj = 0; jj < 16; ++jj) {
        float s = 0.f;
        #pragma unroll
        for (int k = 0; k < 16; ++k) s += v[k] * w2s[k * 16 + jj];
        o[jj] = s;
    }
    float4* ho = (float4*)(hh2 + (size_t)i * 16);
    float4* ao = (float4*)(agg2 + (size_t)i * 16);
    ho[0] = make_float4(o[0]*dv,  o[1]*dv,  o[2]*dv,  o[3]*dv);
    ho[1] = make_float4(o[4]*dv,  o[5]*dv,  o[6]*dv,  o[7]*dv);
    ho[2] = make_float4(o[8]*dv,  o[9]*dv,  o[10]*dv, o[11]*dv);
    ho[3] = make_float4(o[12]*dv, o[13]*dv, o[14]*dv, o[15]*dv);
    ao[0] = make_float4(o[0]*dv2+b2s[0],  o[1]*dv2+b2s[1],  o[2]*dv2+b2s[2],  o[3]*dv2+b2s[3]);
    ao[1] = make_float4(o[4]*dv2+b2s[4],  o[5]*dv2+b2s[5],  o[6]*dv2+b2s[6],  o[7]*dv2+b2s[7]);
    ao[2] = make_float4(o[8]*dv2+b2s[8],  o[9]*dv2+b2s[9],  o[10]*dv2+b2s[10],o[11]*dv2+b2s[11]);
    ao[3] = make_float4(o[12]*dv2+b2s[12],o[13]*dv2+b2s[13],o[14]*dv2+b2s[14],o[15]*dv2+b2s[15]);
}

// ---------------------------------------------------------------------------
// K9: log_softmax over 16 classes
__global__ __launch_bounds__(256) void lsm_kernel(const float* __restrict__ agg2,
                                                  float* __restrict__ out) {
    int i = blockIdx.x * 256 + threadIdx.x;
    if (i >= N_NODES) return;
    float v[16];
    const float4* ar = (const float4*)(agg2 + (size_t)i * 16);
    float4 r0 = ar[0], r1 = ar[1], r2 = ar[2], r3 = ar[3];
    v[0]=r0.x; v[1]=r0.y; v[2]=r0.z; v[3]=r0.w;
    v[4]=r1.x; v[5]=r1.y; v[6]=r1.z; v[7]=r1.w;
    v[8]=r2.x; v[9]=r2.y; v[10]=r2.z; v[11]=r2.w;
    v[12]=r3.x; v[13]=r3.y; v[14]=r3.z; v[15]=r3.w;
    float m = v[0];
    #pragma unroll
    for (int k = 1; k < 16; ++k) m = fmaxf(m, v[k]);
    float ssum = 0.f;
    #pragma unroll
    for (int k = 0; k < 16; ++k) ssum += expf(v[k] - m);
    float l = m + logf(ssum);
    float4* oo = (float4*)(out + (size_t)i * 16);
    oo[0] = make_float4(v[0]-l, v[1]-l, v[2]-l, v[3]-l);
    oo[1] = make_float4(v[4]-l, v[5]-l, v[6]-l, v[7]-l);
    oo[2] = make_float4(v[8]-l, v[9]-l, v[10]-l, v[11]-l);
    oo[3] = make_float4(v[12]-l, v[13]-l, v[14]-l, v[15]-l);
}

// ---------------------------------------------------------------------------
extern "C" void kernel_launch(void* const* d_in, const int* in_sizes, int n_in,
                              void* d_out, int out_size, void* d_ws, size_t ws_size,
                              hipStream_t stream) {
    const float* x    = (const float*)d_in[0];
    const float* W1   = (const float*)d_in[1];
    const float* b1   = (const float*)d_in[2];
    const float* W2   = (const float*)d_in[3];
    const float* b2   = (const float*)d_in[4];
    const int*   ei   = (const int*)d_in[5];
    const int*   src  = ei;             // edge_index[0]
    const int*   dst  = ei + N_EDGES;   // edge_index[1]
    float* out = (float*)d_out;

    // workspace layout (4-byte words); total ~39.2 MB
    int*   wsi  = (int*)d_ws;
    float* wsf  = (float*)d_ws;
    int*   gcnt  = wsi;                        // [NBKT]
    int*   bbase = wsi + 512;                  // [NBKT+1]
    int*   gcur  = wsi + 1024;                 // [NBKT]
    float* dinv  = wsf + 2048;                 // [NPAD]
    int*   row   = wsi + 2048 + NPAD;          // [N+1]
    int*   csr   = wsi + 2048 + 2 * NPAD;      // [E]  (binned & csr share this)
    unsigned int* binned = (unsigned int*)csr;
    float* hh    = wsf + 2048 + 2 * NPAD + N_EDGES;    // [N*16]
    float* agg1  = hh   + (size_t)N_NODES * 16;        // [N*16]
    float* hh2   = agg1 + (size_t)N_NODES * 16;        // [N*16]
    float* agg2  = hh2  + (size_t)N_NODES * 16;        // [N*16]

    const int NB = (N_NODES + 255) / 256;      // 391
    const int GB = N_NODES / 16;               // 6250 (exact)

    hipMemsetAsync(gcnt, 0, NBKT * sizeof(int), stream);
    bin_count_kernel <<<SBLK, 1024, 0, stream>>>(dst, gcnt);
    bucket_scan_kernel<<<1, 512, 0, stream>>>(gcnt, bbase, gcur);
    bin_scatter_kernel<<<SBLK, 1024, 0, stream>>>(src, dst, gcur, binned);
    csr_bucket_kernel<<<NBKT, 1024, 0, stream>>>(binned, bbase, row, csr, dinv);
    gemm1_kernel<<<GB, 256, 0, stream>>>(x, W1, b1, dinv, hh, agg1);
    pull_kernel<<<GB, 256, 0, stream>>>(hh, dinv, row, csr, agg1);
    layer2_kernel<<<NB, 256, 0, stream>>>(agg1, W2, b2, dinv, hh2, agg2);
    pull_kernel<<<GB, 256, 0, stream>>>(hh2, dinv, row, csr, agg2);
    lsm_kernel<<<NB, 256, 0, stream>>>(agg2, out);
}